// Round 2
// baseline (25822.964 us; speedup 1.0000x reference)
//
#include <hip/hip_runtime.h>
#include <hip/hip_cooperative_groups.h>
#include <cstdint>
#include <cstddef>

namespace cg = cooperative_groups;

#define BB   64      // batch
#define TT   256     // time steps
#define EE   300     // embed dim
#define HH   512     // hidden
#define G4H  2048    // 4*H
#define NCLS 18
#define DFF  256

__device__ __forceinline__ float fast_exp2(float x) { return __builtin_amdgcn_exp2f(x); }
__device__ __forceinline__ float sigmoid_f(float x) {
  return 1.0f / (1.0f + fast_exp2(x * -1.442695040888963f));
}
__device__ __forceinline__ float tanh_f(float x) {
  return 2.0f / (1.0f + fast_exp2(x * -2.885390081777927f)) - 1.0f;
}

// ---------------------------------------------------------------------------
// Kernel A: embedding gather + input projection for a chunk of timesteps.
// Block = 256 threads (4 waves). blockIdx.x = tl*128 + rs; each block computes
// 16 gate-rows x 64 batch for one t. Wave w owns k-slice [76w, 76w+klen).
// Lane = batch element. W rows are wave-uniform -> s_load; x-slice in VGPRs.
// Writes xW[tl][row][b] = sum_k W_ih[tag][row][k]*x[b][k] + b_ih + b_hh.
// ---------------------------------------------------------------------------
__global__ __launch_bounds__(256) void xproj_kernel(
    const int* __restrict__ tokens, const int* __restrict__ tags,
    const float* __restrict__ emb, const float* __restrict__ W_ih,
    const float* __restrict__ b_ih, const float* __restrict__ b_hh,
    float* __restrict__ xW, int t0)
{
  const int tid  = threadIdx.x;
  const int lane = tid & 63;
  const int w    = tid >> 6;                  // wave 0..3
  const int rs   = blockIdx.x & 127;          // row-slice (16 rows each)
  const int tl   = blockIdx.x >> 7;           // t within chunk
  const int t    = t0 + tl;
  const int tag  = tags[t];
  const int row0 = rs * 16;
  const int kbeg = __builtin_amdgcn_readfirstlane(w * 76);
  const bool full = (w != 3);                 // waves 0..2: 76 k's, wave 3: 72

  // gather this lane's x-slice (contiguous within one emb row, 16B aligned)
  const int tok = tokens[lane * TT + t];
  const float* xrow = emb + (size_t)tok * EE + kbeg;
  float xr[76];
  #pragma unroll
  for (int i = 0; i < 18; ++i) {
    const float4 v = *reinterpret_cast<const float4*>(xrow + i * 4);
    xr[i*4+0] = v.x; xr[i*4+1] = v.y; xr[i*4+2] = v.z; xr[i*4+3] = v.w;
  }
  if (full) {
    const float4 v = *reinterpret_cast<const float4*>(xrow + 72);
    xr[72] = v.x; xr[73] = v.y; xr[74] = v.z; xr[75] = v.w;
  } else {
    xr[72] = 0.f; xr[73] = 0.f; xr[74] = 0.f; xr[75] = 0.f;
  }

  const float* Wbase = W_ih + (size_t)tag * ((size_t)G4H * EE);
  __shared__ float red[4][16][64];
  #pragma unroll
  for (int r = 0; r < 16; ++r) {
    const float* Wr = Wbase + (size_t)(row0 + r) * EE + kbeg;  // uniform -> s_load
    float a = 0.f;
    #pragma unroll
    for (int k = 0; k < 72; ++k) a = fmaf(Wr[k], xr[k], a);
    if (full) {
      #pragma unroll
      for (int k = 72; k < 76; ++k) a = fmaf(Wr[k], xr[k], a);
    }
    red[w][r][lane] = a;
  }
  __syncthreads();
  #pragma unroll
  for (int it = 0; it < 4; ++it) {
    const int item = tid + it * 256;          // 16*64 = 1024 items
    const int r = item >> 6, b = item & 63;
    const int row = row0 + r;
    float s = red[0][r][b] + red[1][r][b] + red[2][r][b] + red[3][r][b];
    s += b_ih[tag * G4H + row] + b_hh[tag * G4H + row];
    xW[((size_t)tl * G4H + row) * BB + b] = s;
  }
}

// ---------------------------------------------------------------------------
// Kernel B: persistent cooperative LSTM recurrence over nsteps timesteps.
// Grid 256 blocks x 1024 threads (1 block/CU, co-resident). Block owns 2
// hidden indices j0,j0+1 (8 gate rows). Wave w owns k-slice of 32. grid.sync()
// between steps replaces 256 kernel launches.
// ---------------------------------------------------------------------------
__global__ __launch_bounds__(1024) void lstm_seq_kernel(
    const int* __restrict__ tags, const float* __restrict__ W_hh,
    const float* __restrict__ xW, float* __restrict__ hA,
    float* __restrict__ hB, float* __restrict__ cst,
    int t0, int nsteps)
{
  cg::grid_group grid = cg::this_grid();
  const int tid  = threadIdx.x;
  const int lane = tid & 63;
  const int w    = tid >> 6;                  // 0..15
  const int j0   = blockIdx.x * 2;
  const int kbeg = __builtin_amdgcn_readfirstlane(w * 32);

  __shared__ float red[16][8][64];
  __shared__ float gate[8][64];

  for (int s = 0; s < nsteps; ++s) {
    const int t   = t0 + s;
    const int tag = tags[t];
    const float* h_in  = (t & 1) ? hB : hA;
    float*       h_out = (t & 1) ? hA : hB;

    float xr[32];
    const float* hp = h_in + (size_t)kbeg * BB + lane;
    #pragma unroll
    for (int i = 0; i < 32; ++i) xr[i] = hp[i * BB];  // coalesced 256B per i

    const float* Wbase = W_hh + (size_t)tag * ((size_t)G4H * HH);
    #pragma unroll
    for (int g = 0; g < 4; ++g) {
      #pragma unroll
      for (int jj = 0; jj < 2; ++jj) {
        const int row = j0 + jj + g * HH;     // PyTorch gate order i,f,g,o
        const float* Wr = Wbase + (size_t)row * HH + kbeg;  // uniform -> s_load
        float a = 0.f;
        #pragma unroll
        for (int k = 0; k < 32; ++k) a = fmaf(Wr[k], xr[k], a);
        red[w][g * 2 + jj][lane] = a;
      }
    }
    __syncthreads();
    if (tid < 512) {
      const int r = tid >> 6, b = tid & 63;
      const int row = j0 + (r & 1) + (r >> 1) * HH;
      float sacc = 0.f;
      #pragma unroll
      for (int ww = 0; ww < 16; ++ww) sacc += red[ww][r][b];
      sacc += xW[((size_t)s * G4H + row) * BB + b];
      gate[r][b] = sacc;
    }
    __syncthreads();
    if (tid < 128) {
      const int jj = tid >> 6, b = tid & 63;
      const int j = j0 + jj;
      const float i_ = sigmoid_f(gate[0 + jj][b]);
      const float f_ = sigmoid_f(gate[2 + jj][b]);
      const float g_ = tanh_f   (gate[4 + jj][b]);
      const float o_ = sigmoid_f(gate[6 + jj][b]);
      const size_t idx = (size_t)j * BB + b;
      const float cv = f_ * cst[idx] + i_ * g_;
      cst[idx] = cv;
      h_out[idx] = o_ * tanh_f(cv);
    }
    __threadfence();   // make h/c visible device-wide before the grid barrier
    grid.sync();
  }
}

// ---------------------------------------------------------------------------
// Head 1: hid[d][b] = relu(b1[d] + sum_k W1[d][k] * h[k][b]).  Grid 32 x 1024.
// ---------------------------------------------------------------------------
__global__ __launch_bounds__(1024) void head1_kernel(
    const float* __restrict__ W1, const float* __restrict__ b1,
    const float* __restrict__ hfin, float* __restrict__ hid)
{
  const int tid  = threadIdx.x;
  const int lane = tid & 63;
  const int w    = tid >> 6;
  const int row0 = blockIdx.x * 8;
  const int kbeg = __builtin_amdgcn_readfirstlane(w * 32);
  float xr[32];
  const float* hp = hfin + (size_t)kbeg * BB + lane;
  #pragma unroll
  for (int i = 0; i < 32; ++i) xr[i] = hp[i * BB];
  __shared__ float red[16][8][64];
  #pragma unroll
  for (int r = 0; r < 8; ++r) {
    const float* Wr = W1 + (size_t)(row0 + r) * HH + kbeg;
    float a = 0.f;
    #pragma unroll
    for (int k = 0; k < 32; ++k) a = fmaf(Wr[k], xr[k], a);
    red[w][r][lane] = a;
  }
  __syncthreads();
  if (tid < 512) {
    const int r = tid >> 6, b = tid & 63;
    float s = 0.f;
    #pragma unroll
    for (int ww = 0; ww < 16; ++ww) s += red[ww][r][b];
    s += b1[row0 + r];
    hid[(size_t)(row0 + r) * BB + b] = fmaxf(s, 0.f);
  }
}

// ---------------------------------------------------------------------------
// Head 2: out[b][r] = b2[r] + sum_d W2[r][d] * hid[d][b].  1 block x 256.
// ---------------------------------------------------------------------------
__global__ __launch_bounds__(256) void head2_kernel(
    const float* __restrict__ W2, const float* __restrict__ b2,
    const float* __restrict__ hid, float* __restrict__ out)
{
  const int tid  = threadIdx.x;
  const int lane = tid & 63;
  const int w    = tid >> 6;                  // 0..3
  const int kbeg = __builtin_amdgcn_readfirstlane(w * 64);
  float xr[64];
  const float* hp = hid + (size_t)kbeg * BB + lane;
  #pragma unroll
  for (int i = 0; i < 64; ++i) xr[i] = hp[i * BB];
  __shared__ float red[4][NCLS][64];
  #pragma unroll
  for (int r = 0; r < NCLS; ++r) {
    const float* Wr = W2 + (size_t)r * DFF + kbeg;
    float a = 0.f;
    #pragma unroll
    for (int k = 0; k < 64; ++k) a = fmaf(Wr[k], xr[k], a);
    red[w][r][lane] = a;
  }
  __syncthreads();
  for (int it = 0; it < 5; ++it) {
    const int item = tid + it * 256;          // 18*64 = 1152 items
    if (item < NCLS * 64) {
      const int r = item >> 6, b = item & 63;
      float s = red[0][r][b] + red[1][r][b] + red[2][r][b] + red[3][r][b];
      out[(size_t)b * NCLS + r] = s + b2[r];
    }
  }
}

// ---------------------------------------------------------------------------
extern "C" void kernel_launch(void* const* d_in, const int* in_sizes, int n_in,
                              void* d_out, int out_size, void* d_ws, size_t ws_size,
                              hipStream_t stream)
{
  const int*   tokens = (const int*)  d_in[0];
  const int*   tags   = (const int*)  d_in[1];
  const float* emb    = (const float*)d_in[2];
  const float* W_ih   = (const float*)d_in[3];
  const float* W_hh   = (const float*)d_in[4];
  const float* b_ih   = (const float*)d_in[5];
  const float* b_hh   = (const float*)d_in[6];
  const float* W1     = (const float*)d_in[7];
  const float* b1     = (const float*)d_in[8];
  const float* W2     = (const float*)d_in[9];
  const float* b2     = (const float*)d_in[10];
  float* out = (float*)d_out;

  // ws layout: [xW chunk][hA][hB][c][hid]; chunk timesteps to fit ws_size.
  const size_t per_t = (size_t)G4H * BB * sizeof(float);   // 512 KB per timestep
  int TCH = 8;
  for (int c = 256; c >= 8; c >>= 1) {
    if ((size_t)c * per_t + (1u << 20) <= ws_size) { TCH = c; break; }
  }
  char* p = (char*)d_ws;
  float* xW  = (float*)p;  p += (size_t)TCH * per_t;
  float* hA  = (float*)p;  p += (size_t)HH * BB * sizeof(float);
  float* hB  = (float*)p;  p += (size_t)HH * BB * sizeof(float);
  float* cst = (float*)p;  p += (size_t)HH * BB * sizeof(float);
  float* hid = (float*)p;

  hipMemsetAsync(hA,  0, (size_t)HH * BB * sizeof(float), stream);   // h0 = 0
  hipMemsetAsync(cst, 0, (size_t)HH * BB * sizeof(float), stream);   // c0 = 0

  for (int c0 = 0; c0 < TT; c0 += TCH) {
    xproj_kernel<<<dim3((unsigned)TCH * 128), dim3(256), 0, stream>>>(
        tokens, tags, emb, W_ih, b_ih, b_hh, xW, c0);
    {
      int t0 = c0, nsteps = TCH;
      void* args[] = { (void*)&tags, (void*)&W_hh, (void*)&xW,
                       (void*)&hA, (void*)&hB, (void*)&cst,
                       (void*)&t0, (void*)&nsteps };
      hipLaunchCooperativeKernel((const void*)lstm_seq_kernel,
                                 dim3(256), dim3(1024), args, 0, stream);
    }
  }
  // T=256 even -> final h in hA
  head1_kernel<<<dim3(32), dim3(1024), 0, stream>>>(W1, b1, hA, hid);
  head2_kernel<<<dim3(1), dim3(256), 0, stream>>>(W2, b2, hid, out);
}

// Round 4
// 2681.308 us; speedup vs baseline: 9.6307x; 9.6307x over previous
//
#include <hip/hip_runtime.h>
#include <cstdint>
#include <cstddef>

#define BB   64      // batch
#define TT   256     // time steps
#define EE   300     // embed dim
#define HH   512     // hidden
#define G4H  2048    // 4*H
#define NCLS 18
#define DFF  256
#define NBLK 256     // lstm grid blocks (1 per CU)

__device__ __forceinline__ float fast_exp2(float x) { return __builtin_amdgcn_exp2f(x); }
__device__ __forceinline__ float sigmoid_f(float x) {
  return 1.0f / (1.0f + fast_exp2(x * -1.442695040888963f));
}
__device__ __forceinline__ float tanh_f(float x) {
  return 2.0f / (1.0f + fast_exp2(x * -2.885390081777927f)) - 1.0f;
}

// ---------------------------------------------------------------------------
// Kernel A: embedding gather + input projection (unchanged from R1, passing).
// ---------------------------------------------------------------------------
__global__ __launch_bounds__(256) void xproj_kernel(
    const int* __restrict__ tokens, const int* __restrict__ tags,
    const float* __restrict__ emb, const float* __restrict__ W_ih,
    const float* __restrict__ b_ih, const float* __restrict__ b_hh,
    float* __restrict__ xW, int t0)
{
  const int tid  = threadIdx.x;
  const int lane = tid & 63;
  const int w    = tid >> 6;                  // wave 0..3
  const int rs   = blockIdx.x & 127;          // row-slice (16 rows each)
  const int tl   = blockIdx.x >> 7;           // t within chunk
  const int t    = t0 + tl;
  const int tag  = tags[t];
  const int row0 = rs * 16;
  const int kbeg = __builtin_amdgcn_readfirstlane(w * 76);
  const bool full = (w != 3);                 // waves 0..2: 76 k's, wave 3: 72

  const int tok = tokens[lane * TT + t];
  const float* xrow = emb + (size_t)tok * EE + kbeg;
  float xr[76];
  #pragma unroll
  for (int i = 0; i < 18; ++i) {
    const float4 v = *reinterpret_cast<const float4*>(xrow + i * 4);
    xr[i*4+0] = v.x; xr[i*4+1] = v.y; xr[i*4+2] = v.z; xr[i*4+3] = v.w;
  }
  if (full) {
    const float4 v = *reinterpret_cast<const float4*>(xrow + 72);
    xr[72] = v.x; xr[73] = v.y; xr[74] = v.z; xr[75] = v.w;
  } else {
    xr[72] = 0.f; xr[73] = 0.f; xr[74] = 0.f; xr[75] = 0.f;
  }

  const float* Wbase = W_ih + (size_t)tag * ((size_t)G4H * EE);
  __shared__ float red[4][16][64];
  #pragma unroll
  for (int r = 0; r < 16; ++r) {
    const float* Wr = Wbase + (size_t)(row0 + r) * EE + kbeg;  // uniform -> s_load
    float a = 0.f;
    #pragma unroll
    for (int k = 0; k < 72; ++k) a = fmaf(Wr[k], xr[k], a);
    if (full) {
      #pragma unroll
      for (int k = 72; k < 76; ++k) a = fmaf(Wr[k], xr[k], a);
    }
    red[w][r][lane] = a;
  }
  __syncthreads();
  #pragma unroll
  for (int it = 0; it < 4; ++it) {
    const int item = tid + it * 256;          // 16*64 = 1024 items
    const int r = item >> 6, b = item & 63;
    const int row = row0 + r;
    float s = red[0][r][b] + red[1][r][b] + red[2][r][b] + red[3][r][b];
    s += b_ih[tag * G4H + row] + b_hh[tag * G4H + row];
    xW[((size_t)tl * G4H + row) * BB + b] = s;
  }
}

// ---------------------------------------------------------------------------
// Kernel B: persistent cooperative LSTM recurrence, custom epoch barrier.
// Grid 256 x 1024. Block owns hidden j0,j0+1. Wave w owns k-slice of 32.
// h ping-pong via sc0/sc1 (IC-coherent, bypass L1/L2) loads/stores; c in
// registers; barrier = relaxed agent atomics (ordering via s_barrier's
// vmcnt(0) drain). W_hh/xW normally cached (read-only -> never stale).
// ---------------------------------------------------------------------------
__global__ __launch_bounds__(1024) void lstm_seq_kernel(
    const int* __restrict__ tags, const float* __restrict__ W_hh,
    const float* __restrict__ xW, float* __restrict__ hA,
    float* __restrict__ hB, float* __restrict__ cst,
    float* __restrict__ hF, unsigned int* __restrict__ bar,
    int t0, int nsteps)
{
  const int tid  = threadIdx.x;
  const int lane = tid & 63;
  const int w    = tid >> 6;                  // 0..15
  const int j0   = blockIdx.x * 2;
  const int kbeg = __builtin_amdgcn_readfirstlane(w * 32);

  __shared__ float red[16][8][64];
  __shared__ float gate[8][64];

  // c is block-private: keep in registers across all steps (tid<128 only)
  const int ejj = tid >> 6, eb = tid & 63;            // epilogue mapping
  const size_t eidx = (size_t)(j0 + ejj) * BB + eb;
  float creg = (tid < 128) ? cst[eidx] : 0.f;         // normal load (boundary-coherent)

  for (int s = 0; s < nsteps; ++s) {
    const int t   = t0 + s;
    const int tag = tags[t];
    const float* h_in  = (t & 1) ? hB : hA;
    float*       h_out = (t & 1) ? hA : hB;

    // --- coherent h load: 32 x global_load_dword sc0 sc1, one vmcnt drain ---
    float xr[32];
    const float* hp0 = h_in + (size_t)kbeg * BB + lane;
    const float* hp1 = hp0 + 16 * BB;
    asm volatile(
      "global_load_dword %0,  %32, off sc0 sc1\n\t"
      "global_load_dword %1,  %32, off offset:256 sc0 sc1\n\t"
      "global_load_dword %2,  %32, off offset:512 sc0 sc1\n\t"
      "global_load_dword %3,  %32, off offset:768 sc0 sc1\n\t"
      "global_load_dword %4,  %32, off offset:1024 sc0 sc1\n\t"
      "global_load_dword %5,  %32, off offset:1280 sc0 sc1\n\t"
      "global_load_dword %6,  %32, off offset:1536 sc0 sc1\n\t"
      "global_load_dword %7,  %32, off offset:1792 sc0 sc1\n\t"
      "global_load_dword %8,  %32, off offset:2048 sc0 sc1\n\t"
      "global_load_dword %9,  %32, off offset:2304 sc0 sc1\n\t"
      "global_load_dword %10, %32, off offset:2560 sc0 sc1\n\t"
      "global_load_dword %11, %32, off offset:2816 sc0 sc1\n\t"
      "global_load_dword %12, %32, off offset:3072 sc0 sc1\n\t"
      "global_load_dword %13, %32, off offset:3328 sc0 sc1\n\t"
      "global_load_dword %14, %32, off offset:3584 sc0 sc1\n\t"
      "global_load_dword %15, %32, off offset:3840 sc0 sc1\n\t"
      "global_load_dword %16, %33, off sc0 sc1\n\t"
      "global_load_dword %17, %33, off offset:256 sc0 sc1\n\t"
      "global_load_dword %18, %33, off offset:512 sc0 sc1\n\t"
      "global_load_dword %19, %33, off offset:768 sc0 sc1\n\t"
      "global_load_dword %20, %33, off offset:1024 sc0 sc1\n\t"
      "global_load_dword %21, %33, off offset:1280 sc0 sc1\n\t"
      "global_load_dword %22, %33, off offset:1536 sc0 sc1\n\t"
      "global_load_dword %23, %33, off offset:1792 sc0 sc1\n\t"
      "global_load_dword %24, %33, off offset:2048 sc0 sc1\n\t"
      "global_load_dword %25, %33, off offset:2304 sc0 sc1\n\t"
      "global_load_dword %26, %33, off offset:2560 sc0 sc1\n\t"
      "global_load_dword %27, %33, off offset:2816 sc0 sc1\n\t"
      "global_load_dword %28, %33, off offset:3072 sc0 sc1\n\t"
      "global_load_dword %29, %33, off offset:3328 sc0 sc1\n\t"
      "global_load_dword %30, %33, off offset:3584 sc0 sc1\n\t"
      "global_load_dword %31, %33, off offset:3840 sc0 sc1\n\t"
      "s_waitcnt vmcnt(0)"
      : "=&v"(xr[0]),  "=&v"(xr[1]),  "=&v"(xr[2]),  "=&v"(xr[3]),
        "=&v"(xr[4]),  "=&v"(xr[5]),  "=&v"(xr[6]),  "=&v"(xr[7]),
        "=&v"(xr[8]),  "=&v"(xr[9]),  "=&v"(xr[10]), "=&v"(xr[11]),
        "=&v"(xr[12]), "=&v"(xr[13]), "=&v"(xr[14]), "=&v"(xr[15]),
        "=&v"(xr[16]), "=&v"(xr[17]), "=&v"(xr[18]), "=&v"(xr[19]),
        "=&v"(xr[20]), "=&v"(xr[21]), "=&v"(xr[22]), "=&v"(xr[23]),
        "=&v"(xr[24]), "=&v"(xr[25]), "=&v"(xr[26]), "=&v"(xr[27]),
        "=&v"(xr[28]), "=&v"(xr[29]), "=&v"(xr[30]), "=&v"(xr[31])
      : "v"(hp0), "v"(hp1)
      : "memory");

    const float* Wbase = W_hh + (size_t)tag * ((size_t)G4H * HH);
    #pragma unroll
    for (int g = 0; g < 4; ++g) {
      #pragma unroll
      for (int jj = 0; jj < 2; ++jj) {
        const int row = j0 + jj + g * HH;     // PyTorch gate order i,f,g,o
        const float* Wr = Wbase + (size_t)row * HH + kbeg;  // uniform -> s_load
        float a = 0.f;
        #pragma unroll
        for (int k = 0; k < 32; ++k) a = fmaf(Wr[k], xr[k], a);
        red[w][g * 2 + jj][lane] = a;
      }
    }
    __syncthreads();
    if (tid < 512) {
      const int r = tid >> 6, b = tid & 63;
      const int row = j0 + (r & 1) + (r >> 1) * HH;
      float sacc = 0.f;
      #pragma unroll
      for (int ww = 0; ww < 16; ++ww) sacc += red[ww][r][b];
      sacc += xW[((size_t)s * G4H + row) * BB + b];
      gate[r][b] = sacc;
    }
    __syncthreads();
    if (tid < 128) {
      const float i_ = sigmoid_f(gate[0 + ejj][eb]);
      const float f_ = sigmoid_f(gate[2 + ejj][eb]);
      const float g_ = tanh_f   (gate[4 + ejj][eb]);
      const float o_ = sigmoid_f(gate[6 + ejj][eb]);
      creg = f_ * creg + i_ * g_;
      const float hval = o_ * tanh_f(creg);
      __hip_atomic_store(&h_out[eidx], hval, __ATOMIC_RELAXED,
                         __HIP_MEMORY_SCOPE_AGENT);          // sc0 sc1 store
      if (t == TT - 1) hF[eidx] = hval;       // normal store for head kernels
    }
    __syncthreads();   // drains each wave's vmcnt -> all h stores visible
    if (s != nsteps - 1) {
      if (tid == 0) {
        const unsigned int target = (unsigned int)(s + 1) * NBLK;
        const unsigned int old =
            __hip_atomic_fetch_add(&bar[0], 1u, __ATOMIC_RELAXED,
                                   __HIP_MEMORY_SCOPE_AGENT);
        if (old == target - 1u) {
          __hip_atomic_store(&bar[32], target, __ATOMIC_RELAXED,
                             __HIP_MEMORY_SCOPE_AGENT);
        } else {
          while (__hip_atomic_load(&bar[32], __ATOMIC_RELAXED,
                                   __HIP_MEMORY_SCOPE_AGENT) < target)
            __builtin_amdgcn_s_sleep(1);
        }
      }
      __syncthreads();
    }
  }
  if (tid < 128) cst[eidx] = creg;            // normal store (boundary-coherent)
}

// ---------------------------------------------------------------------------
// Head 1: hid[d][b] = relu(b1[d] + sum_k W1[d][k] * h[k][b]).  Grid 32 x 1024.
// ---------------------------------------------------------------------------
__global__ __launch_bounds__(1024) void head1_kernel(
    const float* __restrict__ W1, const float* __restrict__ b1,
    const float* __restrict__ hfin, float* __restrict__ hid)
{
  const int tid  = threadIdx.x;
  const int lane = tid & 63;
  const int w    = tid >> 6;
  const int row0 = blockIdx.x * 8;
  const int kbeg = __builtin_amdgcn_readfirstlane(w * 32);
  float xr[32];
  const float* hp = hfin + (size_t)kbeg * BB + lane;
  #pragma unroll
  for (int i = 0; i < 32; ++i) xr[i] = hp[i * BB];
  __shared__ float red[16][8][64];
  #pragma unroll
  for (int r = 0; r < 8; ++r) {
    const float* Wr = W1 + (size_t)(row0 + r) * HH + kbeg;
    float a = 0.f;
    #pragma unroll
    for (int k = 0; k < 32; ++k) a = fmaf(Wr[k], xr[k], a);
    red[w][r][lane] = a;
  }
  __syncthreads();
  if (tid < 512) {
    const int r = tid >> 6, b = tid & 63;
    float s = 0.f;
    #pragma unroll
    for (int ww = 0; ww < 16; ++ww) s += red[ww][r][b];
    s += b1[row0 + r];
    hid[(size_t)(row0 + r) * BB + b] = fmaxf(s, 0.f);
  }
}

// ---------------------------------------------------------------------------
// Head 2: out[b][r] = b2[r] + sum_d W2[r][d] * hid[d][b].  1 block x 256.
// ---------------------------------------------------------------------------
__global__ __launch_bounds__(256) void head2_kernel(
    const float* __restrict__ W2, const float* __restrict__ b2,
    const float* __restrict__ hid, float* __restrict__ out)
{
  const int tid  = threadIdx.x;
  const int lane = tid & 63;
  const int w    = tid >> 6;                  // 0..3
  const int kbeg = __builtin_amdgcn_readfirstlane(w * 64);
  float xr[64];
  const float* hp = hid + (size_t)kbeg * BB + lane;
  #pragma unroll
  for (int i = 0; i < 64; ++i) xr[i] = hp[i * BB];
  __shared__ float red[4][NCLS][64];
  #pragma unroll
  for (int r = 0; r < NCLS; ++r) {
    const float* Wr = W2 + (size_t)r * DFF + kbeg;
    float a = 0.f;
    #pragma unroll
    for (int k = 0; k < 64; ++k) a = fmaf(Wr[k], xr[k], a);
    red[w][r][lane] = a;
  }
  __syncthreads();
  for (int it = 0; it < 5; ++it) {
    const int item = tid + it * 256;          // 18*64 = 1152 items
    if (item < NCLS * 64) {
      const int r = item >> 6, b = item & 63;
      float s = red[0][r][b] + red[1][r][b] + red[2][r][b] + red[3][r][b];
      out[(size_t)b * NCLS + r] = s + b2[r];
    }
  }
}

// ---------------------------------------------------------------------------
extern "C" void kernel_launch(void* const* d_in, const int* in_sizes, int n_in,
                              void* d_out, int out_size, void* d_ws, size_t ws_size,
                              hipStream_t stream)
{
  const int*   tokens = (const int*)  d_in[0];
  const int*   tags   = (const int*)  d_in[1];
  const float* emb    = (const float*)d_in[2];
  const float* W_ih   = (const float*)d_in[3];
  const float* W_hh   = (const float*)d_in[4];
  const float* b_ih   = (const float*)d_in[5];
  const float* b_hh   = (const float*)d_in[6];
  const float* W1     = (const float*)d_in[7];
  const float* b1     = (const float*)d_in[8];
  const float* W2     = (const float*)d_in[9];
  const float* b2     = (const float*)d_in[10];
  float* out = (float*)d_out;

  // ws layout: [xW chunk][hA][hB][cst][hF][hid][bar]
  const size_t per_t = (size_t)G4H * BB * sizeof(float);   // 512 KB per timestep
  int TCH = 8;
  for (int c = 256; c >= 8; c >>= 1) {
    if ((size_t)c * per_t + (4u << 20) <= ws_size) { TCH = c; break; }
  }
  char* p = (char*)d_ws;
  float* xW  = (float*)p;  p += (size_t)TCH * per_t;
  float* hA  = (float*)p;  p += (size_t)HH * BB * sizeof(float);
  float* hB  = (float*)p;  p += (size_t)HH * BB * sizeof(float);
  float* cst = (float*)p;  p += (size_t)HH * BB * sizeof(float);
  float* hF  = (float*)p;  p += (size_t)HH * BB * sizeof(float);
  float* hid = (float*)p;  p += (size_t)DFF * BB * sizeof(float);
  unsigned int* bar = (unsigned int*)p;

  (void)hipMemsetAsync(hA,  0, (size_t)HH * BB * sizeof(float), stream); // h0 = 0
  (void)hipMemsetAsync(cst, 0, (size_t)HH * BB * sizeof(float), stream); // c0 = 0

  for (int c0 = 0; c0 < TT; c0 += TCH) {
    xproj_kernel<<<dim3((unsigned)TCH * 128), dim3(256), 0, stream>>>(
        tokens, tags, emb, W_ih, b_ih, b_hh, xW, c0);
    (void)hipMemsetAsync(bar, 0, 256, stream);   // reset barrier epoch state
    {
      int t0 = c0, nsteps = TCH;
      void* args[] = { (void*)&tags, (void*)&W_hh, (void*)&xW,
                       (void*)&hA, (void*)&hB, (void*)&cst, (void*)&hF,
                       (void*)&bar, (void*)&t0, (void*)&nsteps };
      hipLaunchCooperativeKernel((const void*)lstm_seq_kernel,
                                 dim3(NBLK), dim3(1024), args, 0, stream);
    }
  }
  head1_kernel<<<dim3(32), dim3(1024), 0, stream>>>(W1, b1, hF, hid);
  head2_kernel<<<dim3(1), dim3(256), 0, stream>>>(W2, b2, hid, out);
}

// Round 5
// 2256.117 us; speedup vs baseline: 11.4458x; 1.1885x over previous
//
#include <hip/hip_runtime.h>
#include <cstdint>
#include <cstddef>

#define BB   64      // batch
#define TT   256     // time steps
#define EE   300     // embed dim
#define HH   512     // hidden
#define G4H  2048    // 4*H
#define NCLS 18
#define DFF  256
#define NBLK 256     // lstm grid blocks (1 per CU)

__device__ __forceinline__ float fast_exp2(float x) { return __builtin_amdgcn_exp2f(x); }
__device__ __forceinline__ float sigmoid_f(float x) {
  return 1.0f / (1.0f + fast_exp2(x * -1.442695040888963f));
}
__device__ __forceinline__ float tanh_f(float x) {
  return 2.0f / (1.0f + fast_exp2(x * -2.885390081777927f)) - 1.0f;
}

// ---------------------------------------------------------------------------
// Kernel A: embedding gather + input projection (unchanged, passing).
// ---------------------------------------------------------------------------
__global__ __launch_bounds__(256) void xproj_kernel(
    const int* __restrict__ tokens, const int* __restrict__ tags,
    const float* __restrict__ emb, const float* __restrict__ W_ih,
    const float* __restrict__ b_ih, const float* __restrict__ b_hh,
    float* __restrict__ xW, int t0)
{
  const int tid  = threadIdx.x;
  const int lane = tid & 63;
  const int w    = tid >> 6;                  // wave 0..3
  const int rs   = blockIdx.x & 127;          // row-slice (16 rows each)
  const int tl   = blockIdx.x >> 7;           // t within chunk
  const int t    = t0 + tl;
  const int tag  = tags[t];
  const int row0 = rs * 16;
  const int kbeg = __builtin_amdgcn_readfirstlane(w * 76);
  const bool full = (w != 3);                 // waves 0..2: 76 k's, wave 3: 72

  const int tok = tokens[lane * TT + t];
  const float* xrow = emb + (size_t)tok * EE + kbeg;
  float xr[76];
  #pragma unroll
  for (int i = 0; i < 18; ++i) {
    const float4 v = *reinterpret_cast<const float4*>(xrow + i * 4);
    xr[i*4+0] = v.x; xr[i*4+1] = v.y; xr[i*4+2] = v.z; xr[i*4+3] = v.w;
  }
  if (full) {
    const float4 v = *reinterpret_cast<const float4*>(xrow + 72);
    xr[72] = v.x; xr[73] = v.y; xr[74] = v.z; xr[75] = v.w;
  } else {
    xr[72] = 0.f; xr[73] = 0.f; xr[74] = 0.f; xr[75] = 0.f;
  }

  const float* Wbase = W_ih + (size_t)tag * ((size_t)G4H * EE);
  __shared__ float red[4][16][64];
  #pragma unroll
  for (int r = 0; r < 16; ++r) {
    const float* Wr = Wbase + (size_t)(row0 + r) * EE + kbeg;  // uniform -> s_load
    float a = 0.f;
    #pragma unroll
    for (int k = 0; k < 72; ++k) a = fmaf(Wr[k], xr[k], a);
    if (full) {
      #pragma unroll
      for (int k = 72; k < 76; ++k) a = fmaf(Wr[k], xr[k], a);
    }
    red[w][r][lane] = a;
  }
  __syncthreads();
  #pragma unroll
  for (int it = 0; it < 4; ++it) {
    const int item = tid + it * 256;          // 16*64 = 1024 items
    const int r = item >> 6, b = item & 63;
    const int row = row0 + r;
    float s = red[0][r][b] + red[1][r][b] + red[2][r][b] + red[3][r][b];
    s += b_ih[tag * G4H + row] + b_hh[tag * G4H + row];
    xW[((size_t)tl * G4H + row) * BB + b] = s;
  }
}

// ---------------------------------------------------------------------------
// Kernel B: persistent cooperative LSTM recurrence.
// Distributed-flag barrier: block i stores flag[i*16]=s+1 (own 64B line),
// then wave 0 of EVERY block polls all 256 flags (64 lanes x 4) until all
// >= s+1. No same-address atomics, single IC round-trip release chain.
// h ping-pong via sc0/sc1 IC-coherent loads/stores; c in registers; xW
// prefetched one step ahead; W_hh/xW normally cached (read-only).
// ---------------------------------------------------------------------------
__global__ __launch_bounds__(1024) void lstm_seq_kernel(
    const int* __restrict__ tags, const float* __restrict__ W_hh,
    const float* __restrict__ xW, float* __restrict__ hA,
    float* __restrict__ hB, float* __restrict__ cst,
    float* __restrict__ hF, unsigned int* __restrict__ flags,
    int t0, int nsteps)
{
  const int tid  = threadIdx.x;
  const int lane = tid & 63;
  const int w    = tid >> 6;                  // 0..15
  const int j0   = blockIdx.x * 2;
  const int kbeg = __builtin_amdgcn_readfirstlane(w * 32);

  __shared__ float red[16][8][64];
  __shared__ float gate[8][64];

  // c is block-private: keep in registers across all steps (tid<128 only)
  const int ejj = tid >> 6, eb = tid & 63;            // epilogue mapping
  const size_t eidx = (size_t)(j0 + ejj) * BB + eb;
  float creg = (tid < 128) ? cst[eidx] : 0.f;         // boundary-coherent load

  // reduce-phase mapping (tid<512) + xW prefetch for step 0
  const int rr = tid >> 6, rb = tid & 63;             // r 0..7 (tid<512)
  const int rrow = j0 + (rr & 1) + (rr >> 1) * HH;
  float xw_cur = 0.f;
  if (tid < 512) xw_cur = xW[((size_t)0 * G4H + rrow) * BB + rb];

  for (int s = 0; s < nsteps; ++s) {
    const int t   = t0 + s;
    const int tag = tags[t];
    const float* h_in  = (t & 1) ? hB : hA;
    float*       h_out = (t & 1) ? hA : hB;

    // --- coherent h load: 32 x global_load_dword sc0 sc1, one vmcnt drain ---
    float xr[32];
    const float* hp0 = h_in + (size_t)kbeg * BB + lane;
    const float* hp1 = hp0 + 16 * BB;
    asm volatile(
      "global_load_dword %0,  %32, off sc0 sc1\n\t"
      "global_load_dword %1,  %32, off offset:256 sc0 sc1\n\t"
      "global_load_dword %2,  %32, off offset:512 sc0 sc1\n\t"
      "global_load_dword %3,  %32, off offset:768 sc0 sc1\n\t"
      "global_load_dword %4,  %32, off offset:1024 sc0 sc1\n\t"
      "global_load_dword %5,  %32, off offset:1280 sc0 sc1\n\t"
      "global_load_dword %6,  %32, off offset:1536 sc0 sc1\n\t"
      "global_load_dword %7,  %32, off offset:1792 sc0 sc1\n\t"
      "global_load_dword %8,  %32, off offset:2048 sc0 sc1\n\t"
      "global_load_dword %9,  %32, off offset:2304 sc0 sc1\n\t"
      "global_load_dword %10, %32, off offset:2560 sc0 sc1\n\t"
      "global_load_dword %11, %32, off offset:2816 sc0 sc1\n\t"
      "global_load_dword %12, %32, off offset:3072 sc0 sc1\n\t"
      "global_load_dword %13, %32, off offset:3328 sc0 sc1\n\t"
      "global_load_dword %14, %32, off offset:3584 sc0 sc1\n\t"
      "global_load_dword %15, %32, off offset:3840 sc0 sc1\n\t"
      "global_load_dword %16, %33, off sc0 sc1\n\t"
      "global_load_dword %17, %33, off offset:256 sc0 sc1\n\t"
      "global_load_dword %18, %33, off offset:512 sc0 sc1\n\t"
      "global_load_dword %19, %33, off offset:768 sc0 sc1\n\t"
      "global_load_dword %20, %33, off offset:1024 sc0 sc1\n\t"
      "global_load_dword %21, %33, off offset:1280 sc0 sc1\n\t"
      "global_load_dword %22, %33, off offset:1536 sc0 sc1\n\t"
      "global_load_dword %23, %33, off offset:1792 sc0 sc1\n\t"
      "global_load_dword %24, %33, off offset:2048 sc0 sc1\n\t"
      "global_load_dword %25, %33, off offset:2304 sc0 sc1\n\t"
      "global_load_dword %26, %33, off offset:2560 sc0 sc1\n\t"
      "global_load_dword %27, %33, off offset:2816 sc0 sc1\n\t"
      "global_load_dword %28, %33, off offset:3072 sc0 sc1\n\t"
      "global_load_dword %29, %33, off offset:3328 sc0 sc1\n\t"
      "global_load_dword %30, %33, off offset:3584 sc0 sc1\n\t"
      "global_load_dword %31, %33, off offset:3840 sc0 sc1\n\t"
      "s_waitcnt vmcnt(0)"
      : "=&v"(xr[0]),  "=&v"(xr[1]),  "=&v"(xr[2]),  "=&v"(xr[3]),
        "=&v"(xr[4]),  "=&v"(xr[5]),  "=&v"(xr[6]),  "=&v"(xr[7]),
        "=&v"(xr[8]),  "=&v"(xr[9]),  "=&v"(xr[10]), "=&v"(xr[11]),
        "=&v"(xr[12]), "=&v"(xr[13]), "=&v"(xr[14]), "=&v"(xr[15]),
        "=&v"(xr[16]), "=&v"(xr[17]), "=&v"(xr[18]), "=&v"(xr[19]),
        "=&v"(xr[20]), "=&v"(xr[21]), "=&v"(xr[22]), "=&v"(xr[23]),
        "=&v"(xr[24]), "=&v"(xr[25]), "=&v"(xr[26]), "=&v"(xr[27]),
        "=&v"(xr[28]), "=&v"(xr[29]), "=&v"(xr[30]), "=&v"(xr[31])
      : "v"(hp0), "v"(hp1)
      : "memory");

    const float* Wbase = W_hh + (size_t)tag * ((size_t)G4H * HH);
    #pragma unroll
    for (int g = 0; g < 4; ++g) {
      #pragma unroll
      for (int jj = 0; jj < 2; ++jj) {
        const int row = j0 + jj + g * HH;     // PyTorch gate order i,f,g,o
        const float* Wr = Wbase + (size_t)row * HH + kbeg;  // uniform -> s_load
        float a = 0.f;
        #pragma unroll
        for (int k = 0; k < 32; ++k) a = fmaf(Wr[k], xr[k], a);
        red[w][g * 2 + jj][lane] = a;
      }
    }
    __syncthreads();
    if (tid < 512) {
      float sacc = 0.f;
      #pragma unroll
      for (int ww = 0; ww < 16; ++ww) sacc += red[ww][rr][rb];
      gate[rr][rb] = sacc + xw_cur;
    }
    __syncthreads();
    if (tid < 128) {
      const float i_ = sigmoid_f(gate[0 + ejj][eb]);
      const float f_ = sigmoid_f(gate[2 + ejj][eb]);
      const float g_ = tanh_f   (gate[4 + ejj][eb]);
      const float o_ = sigmoid_f(gate[6 + ejj][eb]);
      creg = f_ * creg + i_ * g_;
      const float hval = o_ * tanh_f(creg);
      __hip_atomic_store(&h_out[eidx], hval, __ATOMIC_RELAXED,
                         __HIP_MEMORY_SCOPE_AGENT);          // sc0 sc1 store
      if (t == TT - 1) hF[eidx] = hval;       // normal store for head kernels
    }
    __syncthreads();   // per-wave vmcnt drained -> all h stores visible (IC)
    if (s != nsteps - 1) {
      // arrive: own flag line, no contention
      if (tid == 0) {
        __hip_atomic_store(&flags[blockIdx.x * 16], (unsigned int)(s + 1),
                           __ATOMIC_RELAXED, __HIP_MEMORY_SCOPE_AGENT);
      }
      // prefetch next step's xW while the barrier settles
      if (tid < 512) xw_cur = xW[((size_t)(s + 1) * G4H + rrow) * BB + rb];
      // poll: wave 0 watches all 256 flags (4 per lane)
      if (w == 0) {
        const unsigned int target = (unsigned int)(s + 1);
        for (;;) {
          const unsigned int f0 = __hip_atomic_load(&flags[(lane      ) * 16],
                                    __ATOMIC_RELAXED, __HIP_MEMORY_SCOPE_AGENT);
          const unsigned int f1 = __hip_atomic_load(&flags[(lane +  64) * 16],
                                    __ATOMIC_RELAXED, __HIP_MEMORY_SCOPE_AGENT);
          const unsigned int f2 = __hip_atomic_load(&flags[(lane + 128) * 16],
                                    __ATOMIC_RELAXED, __HIP_MEMORY_SCOPE_AGENT);
          const unsigned int f3 = __hip_atomic_load(&flags[(lane + 192) * 16],
                                    __ATOMIC_RELAXED, __HIP_MEMORY_SCOPE_AGENT);
          if (__all(f0 >= target && f1 >= target && f2 >= target && f3 >= target))
            break;
        }
      }
      __syncthreads();   // release the other 15 waves
    }
  }
  if (tid < 128) cst[eidx] = creg;            // boundary-coherent store
}

// ---------------------------------------------------------------------------
// Head 1: hid[d][b] = relu(b1[d] + sum_k W1[d][k] * h[k][b]).  Grid 32 x 1024.
// ---------------------------------------------------------------------------
__global__ __launch_bounds__(1024) void head1_kernel(
    const float* __restrict__ W1, const float* __restrict__ b1,
    const float* __restrict__ hfin, float* __restrict__ hid)
{
  const int tid  = threadIdx.x;
  const int lane = tid & 63;
  const int w    = tid >> 6;
  const int row0 = blockIdx.x * 8;
  const int kbeg = __builtin_amdgcn_readfirstlane(w * 32);
  float xr[32];
  const float* hp = hfin + (size_t)kbeg * BB + lane;
  #pragma unroll
  for (int i = 0; i < 32; ++i) xr[i] = hp[i * BB];
  __shared__ float red[16][8][64];
  #pragma unroll
  for (int r = 0; r < 8; ++r) {
    const float* Wr = W1 + (size_t)(row0 + r) * HH + kbeg;
    float a = 0.f;
    #pragma unroll
    for (int k = 0; k < 32; ++k) a = fmaf(Wr[k], xr[k], a);
    red[w][r][lane] = a;
  }
  __syncthreads();
  if (tid < 512) {
    const int r = tid >> 6, b = tid & 63;
    float s = 0.f;
    #pragma unroll
    for (int ww = 0; ww < 16; ++ww) s += red[ww][r][b];
    s += b1[row0 + r];
    hid[(size_t)(row0 + r) * BB + b] = fmaxf(s, 0.f);
  }
}

// ---------------------------------------------------------------------------
// Head 2: out[b][r] = b2[r] + sum_d W2[r][d] * hid[d][b].  1 block x 256.
// ---------------------------------------------------------------------------
__global__ __launch_bounds__(256) void head2_kernel(
    const float* __restrict__ W2, const float* __restrict__ b2,
    const float* __restrict__ hid, float* __restrict__ out)
{
  const int tid  = threadIdx.x;
  const int lane = tid & 63;
  const int w    = tid >> 6;                  // 0..3
  const int kbeg = __builtin_amdgcn_readfirstlane(w * 64);
  float xr[64];
  const float* hp = hid + (size_t)kbeg * BB + lane;
  #pragma unroll
  for (int i = 0; i < 64; ++i) xr[i] = hp[i * BB];
  __shared__ float red[4][NCLS][64];
  #pragma unroll
  for (int r = 0; r < NCLS; ++r) {
    const float* Wr = W2 + (size_t)r * DFF + kbeg;
    float a = 0.f;
    #pragma unroll
    for (int k = 0; k < 64; ++k) a = fmaf(Wr[k], xr[k], a);
    red[w][r][lane] = a;
  }
  __syncthreads();
  for (int it = 0; it < 5; ++it) {
    const int item = tid + it * 256;          // 18*64 = 1152 items
    if (item < NCLS * 64) {
      const int r = item >> 6, b = item & 63;
      float s = red[0][r][b] + red[1][r][b] + red[2][r][b] + red[3][r][b];
      out[(size_t)b * NCLS + r] = s + b2[r];
    }
  }
}

// ---------------------------------------------------------------------------
extern "C" void kernel_launch(void* const* d_in, const int* in_sizes, int n_in,
                              void* d_out, int out_size, void* d_ws, size_t ws_size,
                              hipStream_t stream)
{
  const int*   tokens = (const int*)  d_in[0];
  const int*   tags   = (const int*)  d_in[1];
  const float* emb    = (const float*)d_in[2];
  const float* W_ih   = (const float*)d_in[3];
  const float* W_hh   = (const float*)d_in[4];
  const float* b_ih   = (const float*)d_in[5];
  const float* b_hh   = (const float*)d_in[6];
  const float* W1     = (const float*)d_in[7];
  const float* b1     = (const float*)d_in[8];
  const float* W2     = (const float*)d_in[9];
  const float* b2     = (const float*)d_in[10];
  float* out = (float*)d_out;

  // ws layout: [xW chunk][hA][hB][cst][hF][hid][flags]
  const size_t per_t = (size_t)G4H * BB * sizeof(float);   // 512 KB per timestep
  int TCH = 8;
  for (int c = 256; c >= 8; c >>= 1) {
    if ((size_t)c * per_t + (4u << 20) <= ws_size) { TCH = c; break; }
  }
  char* p = (char*)d_ws;
  float* xW  = (float*)p;  p += (size_t)TCH * per_t;
  float* hA  = (float*)p;  p += (size_t)HH * BB * sizeof(float);
  float* hB  = (float*)p;  p += (size_t)HH * BB * sizeof(float);
  float* cst = (float*)p;  p += (size_t)HH * BB * sizeof(float);
  float* hF  = (float*)p;  p += (size_t)HH * BB * sizeof(float);
  float* hid = (float*)p;  p += (size_t)DFF * BB * sizeof(float);
  unsigned int* flags = (unsigned int*)p;      // 256 * 16 dwords = 16 KB

  (void)hipMemsetAsync(hA,  0, (size_t)HH * BB * sizeof(float), stream); // h0 = 0
  (void)hipMemsetAsync(cst, 0, (size_t)HH * BB * sizeof(float), stream); // c0 = 0

  for (int c0 = 0; c0 < TT; c0 += TCH) {
    xproj_kernel<<<dim3((unsigned)TCH * 128), dim3(256), 0, stream>>>(
        tokens, tags, emb, W_ih, b_ih, b_hh, xW, c0);
    (void)hipMemsetAsync(flags, 0, NBLK * 16 * sizeof(unsigned int), stream);
    {
      int t0 = c0, nsteps = TCH;
      void* args[] = { (void*)&tags, (void*)&W_hh, (void*)&xW,
                       (void*)&hA, (void*)&hB, (void*)&cst, (void*)&hF,
                       (void*)&flags, (void*)&t0, (void*)&nsteps };
      hipLaunchCooperativeKernel((const void*)lstm_seq_kernel,
                                 dim3(NBLK), dim3(1024), args, 0, stream);
    }
  }
  head1_kernel<<<dim3(32), dim3(1024), 0, stream>>>(W1, b1, hF, hid);
  head2_kernel<<<dim3(1), dim3(256), 0, stream>>>(W2, b2, hid, out);
}

// Round 6
// 1864.274 us; speedup vs baseline: 13.8515x; 1.2102x over previous
//
#include <hip/hip_runtime.h>
#include <cstdint>
#include <cstddef>

#define BB   64      // batch
#define TT   256     // time steps
#define EE   300     // embed dim
#define HH   512     // hidden
#define G4H  2048    // 4*H
#define NCLS 18
#define DFF  256
#define NBLK 256     // lstm grid blocks (1 per CU)

__device__ __forceinline__ float fast_exp2(float x) { return __builtin_amdgcn_exp2f(x); }
__device__ __forceinline__ float sigmoid_f(float x) {
  return 1.0f / (1.0f + fast_exp2(x * -1.442695040888963f));
}
__device__ __forceinline__ float tanh_f(float x) {
  return 2.0f / (1.0f + fast_exp2(x * -2.885390081777927f)) - 1.0f;
}

// ---------------------------------------------------------------------------
// Kernel A: embedding gather + input projection (unchanged, passing).
// ---------------------------------------------------------------------------
__global__ __launch_bounds__(256) void xproj_kernel(
    const int* __restrict__ tokens, const int* __restrict__ tags,
    const float* __restrict__ emb, const float* __restrict__ W_ih,
    const float* __restrict__ b_ih, const float* __restrict__ b_hh,
    float* __restrict__ xW, int t0)
{
  const int tid  = threadIdx.x;
  const int lane = tid & 63;
  const int w    = tid >> 6;                  // wave 0..3
  const int rs   = blockIdx.x & 127;          // row-slice (16 rows each)
  const int tl   = blockIdx.x >> 7;           // t within chunk
  const int t    = t0 + tl;
  const int tag  = tags[t];
  const int row0 = rs * 16;
  const int kbeg = __builtin_amdgcn_readfirstlane(w * 76);
  const bool full = (w != 3);                 // waves 0..2: 76 k's, wave 3: 72

  const int tok = tokens[lane * TT + t];
  const float* xrow = emb + (size_t)tok * EE + kbeg;
  float xr[76];
  #pragma unroll
  for (int i = 0; i < 18; ++i) {
    const float4 v = *reinterpret_cast<const float4*>(xrow + i * 4);
    xr[i*4+0] = v.x; xr[i*4+1] = v.y; xr[i*4+2] = v.z; xr[i*4+3] = v.w;
  }
  if (full) {
    const float4 v = *reinterpret_cast<const float4*>(xrow + 72);
    xr[72] = v.x; xr[73] = v.y; xr[74] = v.z; xr[75] = v.w;
  } else {
    xr[72] = 0.f; xr[73] = 0.f; xr[74] = 0.f; xr[75] = 0.f;
  }

  const float* Wbase = W_ih + (size_t)tag * ((size_t)G4H * EE);
  __shared__ float red[4][16][64];
  #pragma unroll
  for (int r = 0; r < 16; ++r) {
    const float* Wr = Wbase + (size_t)(row0 + r) * EE + kbeg;  // uniform -> s_load
    float a = 0.f;
    #pragma unroll
    for (int k = 0; k < 72; ++k) a = fmaf(Wr[k], xr[k], a);
    if (full) {
      #pragma unroll
      for (int k = 72; k < 76; ++k) a = fmaf(Wr[k], xr[k], a);
    }
    red[w][r][lane] = a;
  }
  __syncthreads();
  #pragma unroll
  for (int it = 0; it < 4; ++it) {
    const int item = tid + it * 256;          // 16*64 = 1024 items
    const int r = item >> 6, b = item & 63;
    const int row = row0 + r;
    float s = red[0][r][b] + red[1][r][b] + red[2][r][b] + red[3][r][b];
    s += b_ih[tag * G4H + row] + b_hh[tag * G4H + row];
    xW[((size_t)tl * G4H + row) * BB + b] = s;
  }
}

// ---------------------------------------------------------------------------
// Kernel B: persistent cooperative LSTM recurrence.
// W_hh block-slice (8 rows x 512 = 16 KB) staged in LDS, double-buffered,
// prefetched ONE STEP AHEAD (tag[t+1] known): coalesced float4 global loads
// right after the h-load, ds_write after the dot -> HBM latency hides under
// compute. Dot reads W via wave-uniform LDS broadcast (no s_load chains).
// Distributed-flag barrier; h ping-pong via sc0/sc1 IC-coherent ops; c in
// registers; xW prefetched one step ahead.
// ---------------------------------------------------------------------------
__global__ __launch_bounds__(1024) void lstm_seq_kernel(
    const int* __restrict__ tags, const float* __restrict__ W_hh,
    const float* __restrict__ xW, float* __restrict__ hA,
    float* __restrict__ hB, float* __restrict__ cst,
    float* __restrict__ hF, unsigned int* __restrict__ flags,
    int t0, int nsteps)
{
  const int tid  = threadIdx.x;
  const int lane = tid & 63;
  const int w    = tid >> 6;                  // 0..15
  const int j0   = blockIdx.x * 2;
  const int kbeg = __builtin_amdgcn_readfirstlane(w * 32);

  __shared__ float red[16][8][64];
  __shared__ float gate[8][64];
  __shared__ float wbuf[2][8][512];           // double-buffered W slice (32 KB)

  // c is block-private: keep in registers across all steps (tid<128 only)
  const int ejj = tid >> 6, eb = tid & 63;            // epilogue mapping
  const size_t eidx = (size_t)(j0 + ejj) * BB + eb;
  float creg = (tid < 128) ? cst[eidx] : 0.f;         // boundary-coherent load

  // reduce-phase mapping (tid<512) + xW prefetch for step 0
  const int rr = tid >> 6, rb = tid & 63;             // r 0..7 (tid<512)
  const int rrow = j0 + (rr & 1) + (rr >> 1) * HH;
  float xw_cur = 0.f;
  if (tid < 512) xw_cur = xW[((size_t)0 * G4H + rrow) * BB + rb];

  // W prefetch mapping: wave w stages row pr = w>>1, half phb = w&1
  const int pr  = w >> 1;
  const int phb = w & 1;
  const size_t prow_off = (size_t)(j0 + (pr & 1) + (pr >> 1) * HH) * HH
                          + phb * 256 + lane * 4;

  // stage W for step 0 into wbuf[0]
  {
    const int tag0 = tags[t0];
    const float4 w0 = *reinterpret_cast<const float4*>(
        W_hh + (size_t)tag0 * ((size_t)G4H * HH) + prow_off);
    *reinterpret_cast<float4*>(&wbuf[0][pr][phb * 256 + lane * 4]) = w0;
  }
  __syncthreads();

  for (int s = 0; s < nsteps; ++s) {
    const int t   = t0 + s;
    const int cur = s & 1;
    const float* h_in  = (t & 1) ? hB : hA;
    float*       h_out = (t & 1) ? hA : hB;

    // --- coherent h load: 32 x global_load_dword sc0 sc1, one vmcnt drain ---
    float xr[32];
    const float* hp0 = h_in + (size_t)kbeg * BB + lane;
    const float* hp1 = hp0 + 16 * BB;
    asm volatile(
      "global_load_dword %0,  %32, off sc0 sc1\n\t"
      "global_load_dword %1,  %32, off offset:256 sc0 sc1\n\t"
      "global_load_dword %2,  %32, off offset:512 sc0 sc1\n\t"
      "global_load_dword %3,  %32, off offset:768 sc0 sc1\n\t"
      "global_load_dword %4,  %32, off offset:1024 sc0 sc1\n\t"
      "global_load_dword %5,  %32, off offset:1280 sc0 sc1\n\t"
      "global_load_dword %6,  %32, off offset:1536 sc0 sc1\n\t"
      "global_load_dword %7,  %32, off offset:1792 sc0 sc1\n\t"
      "global_load_dword %8,  %32, off offset:2048 sc0 sc1\n\t"
      "global_load_dword %9,  %32, off offset:2304 sc0 sc1\n\t"
      "global_load_dword %10, %32, off offset:2560 sc0 sc1\n\t"
      "global_load_dword %11, %32, off offset:2816 sc0 sc1\n\t"
      "global_load_dword %12, %32, off offset:3072 sc0 sc1\n\t"
      "global_load_dword %13, %32, off offset:3328 sc0 sc1\n\t"
      "global_load_dword %14, %32, off offset:3584 sc0 sc1\n\t"
      "global_load_dword %15, %32, off offset:3840 sc0 sc1\n\t"
      "global_load_dword %16, %33, off sc0 sc1\n\t"
      "global_load_dword %17, %33, off offset:256 sc0 sc1\n\t"
      "global_load_dword %18, %33, off offset:512 sc0 sc1\n\t"
      "global_load_dword %19, %33, off offset:768 sc0 sc1\n\t"
      "global_load_dword %20, %33, off offset:1024 sc0 sc1\n\t"
      "global_load_dword %21, %33, off offset:1280 sc0 sc1\n\t"
      "global_load_dword %22, %33, off offset:1536 sc0 sc1\n\t"
      "global_load_dword %23, %33, off offset:1792 sc0 sc1\n\t"
      "global_load_dword %24, %33, off offset:2048 sc0 sc1\n\t"
      "global_load_dword %25, %33, off offset:2304 sc0 sc1\n\t"
      "global_load_dword %26, %33, off offset:2560 sc0 sc1\n\t"
      "global_load_dword %27, %33, off offset:2816 sc0 sc1\n\t"
      "global_load_dword %28, %33, off offset:3072 sc0 sc1\n\t"
      "global_load_dword %29, %33, off offset:3328 sc0 sc1\n\t"
      "global_load_dword %30, %33, off offset:3584 sc0 sc1\n\t"
      "global_load_dword %31, %33, off offset:3840 sc0 sc1\n\t"
      "s_waitcnt vmcnt(0)"
      : "=&v"(xr[0]),  "=&v"(xr[1]),  "=&v"(xr[2]),  "=&v"(xr[3]),
        "=&v"(xr[4]),  "=&v"(xr[5]),  "=&v"(xr[6]),  "=&v"(xr[7]),
        "=&v"(xr[8]),  "=&v"(xr[9]),  "=&v"(xr[10]), "=&v"(xr[11]),
        "=&v"(xr[12]), "=&v"(xr[13]), "=&v"(xr[14]), "=&v"(xr[15]),
        "=&v"(xr[16]), "=&v"(xr[17]), "=&v"(xr[18]), "=&v"(xr[19]),
        "=&v"(xr[20]), "=&v"(xr[21]), "=&v"(xr[22]), "=&v"(xr[23]),
        "=&v"(xr[24]), "=&v"(xr[25]), "=&v"(xr[26]), "=&v"(xr[27]),
        "=&v"(xr[28]), "=&v"(xr[29]), "=&v"(xr[30]), "=&v"(xr[31])
      : "v"(hp0), "v"(hp1)
      : "memory");

    // --- issue next-step W prefetch (coalesced, hides under the dot) ---
    const bool pre = (s + 1 < nsteps);
    float4 wpre;
    if (pre) {
      const int ntag = tags[t + 1];
      wpre = *reinterpret_cast<const float4*>(
          W_hh + (size_t)ntag * ((size_t)G4H * HH) + prow_off);
    }

    // --- dot from LDS wbuf[cur]: wave-uniform broadcast reads ---
    #pragma unroll
    for (int g = 0; g < 4; ++g) {
      #pragma unroll
      for (int jj = 0; jj < 2; ++jj) {
        const int r = g * 2 + jj;
        const float* Wr = &wbuf[cur][r][kbeg];
        float a = 0.f;
        #pragma unroll
        for (int i = 0; i < 8; ++i) {
          const float4 wv = *reinterpret_cast<const float4*>(Wr + i * 4);
          a = fmaf(wv.x, xr[i*4+0], a);
          a = fmaf(wv.y, xr[i*4+1], a);
          a = fmaf(wv.z, xr[i*4+2], a);
          a = fmaf(wv.w, xr[i*4+3], a);
        }
        red[w][r][lane] = a;
      }
    }

    // --- land the W prefetch into the alternate buffer ---
    if (pre) {
      *reinterpret_cast<float4*>(&wbuf[cur ^ 1][pr][phb * 256 + lane * 4]) = wpre;
    }
    __syncthreads();

    if (tid < 512) {
      float sacc = 0.f;
      #pragma unroll
      for (int ww = 0; ww < 16; ++ww) sacc += red[ww][rr][rb];
      gate[rr][rb] = sacc + xw_cur;
    }
    __syncthreads();
    if (tid < 128) {
      const float i_ = sigmoid_f(gate[0 + ejj][eb]);
      const float f_ = sigmoid_f(gate[2 + ejj][eb]);
      const float g_ = tanh_f   (gate[4 + ejj][eb]);
      const float o_ = sigmoid_f(gate[6 + ejj][eb]);
      creg = f_ * creg + i_ * g_;
      const float hval = o_ * tanh_f(creg);
      __hip_atomic_store(&h_out[eidx], hval, __ATOMIC_RELAXED,
                         __HIP_MEMORY_SCOPE_AGENT);          // sc0 sc1 store
      if (t == TT - 1) hF[eidx] = hval;       // normal store for head kernels
    }
    __syncthreads();   // per-wave vmcnt drained -> all h stores visible (IC)
    if (s != nsteps - 1) {
      // arrive: own flag line, no contention
      if (tid == 0) {
        __hip_atomic_store(&flags[blockIdx.x * 16], (unsigned int)(s + 1),
                           __ATOMIC_RELAXED, __HIP_MEMORY_SCOPE_AGENT);
      }
      // prefetch next step's xW while the barrier settles
      if (tid < 512) xw_cur = xW[((size_t)(s + 1) * G4H + rrow) * BB + rb];
      // poll: wave 0 watches all 256 flags (4 per lane)
      if (w == 0) {
        const unsigned int target = (unsigned int)(s + 1);
        for (;;) {
          const unsigned int f0 = __hip_atomic_load(&flags[(lane      ) * 16],
                                    __ATOMIC_RELAXED, __HIP_MEMORY_SCOPE_AGENT);
          const unsigned int f1 = __hip_atomic_load(&flags[(lane +  64) * 16],
                                    __ATOMIC_RELAXED, __HIP_MEMORY_SCOPE_AGENT);
          const unsigned int f2 = __hip_atomic_load(&flags[(lane + 128) * 16],
                                    __ATOMIC_RELAXED, __HIP_MEMORY_SCOPE_AGENT);
          const unsigned int f3 = __hip_atomic_load(&flags[(lane + 192) * 16],
                                    __ATOMIC_RELAXED, __HIP_MEMORY_SCOPE_AGENT);
          if (__all(f0 >= target && f1 >= target && f2 >= target && f3 >= target))
            break;
        }
      }
      __syncthreads();   // release the other 15 waves
    }
  }
  if (tid < 128) cst[eidx] = creg;            // boundary-coherent store
}

// ---------------------------------------------------------------------------
// Head 1: hid[d][b] = relu(b1[d] + sum_k W1[d][k] * h[k][b]).  Grid 32 x 1024.
// ---------------------------------------------------------------------------
__global__ __launch_bounds__(1024) void head1_kernel(
    const float* __restrict__ W1, const float* __restrict__ b1,
    const float* __restrict__ hfin, float* __restrict__ hid)
{
  const int tid  = threadIdx.x;
  const int lane = tid & 63;
  const int w    = tid >> 6;
  const int row0 = blockIdx.x * 8;
  const int kbeg = __builtin_amdgcn_readfirstlane(w * 32);
  float xr[32];
  const float* hp = hfin + (size_t)kbeg * BB + lane;
  #pragma unroll
  for (int i = 0; i < 32; ++i) xr[i] = hp[i * BB];
  __shared__ float red[16][8][64];
  #pragma unroll
  for (int r = 0; r < 8; ++r) {
    const float* Wr = W1 + (size_t)(row0 + r) * HH + kbeg;
    float a = 0.f;
    #pragma unroll
    for (int k = 0; k < 32; ++k) a = fmaf(Wr[k], xr[k], a);
    red[w][r][lane] = a;
  }
  __syncthreads();
  if (tid < 512) {
    const int r = tid >> 6, b = tid & 63;
    float s = 0.f;
    #pragma unroll
    for (int ww = 0; ww < 16; ++ww) s += red[ww][r][b];
    s += b1[row0 + r];
    hid[(size_t)(row0 + r) * BB + b] = fmaxf(s, 0.f);
  }
}

// ---------------------------------------------------------------------------
// Head 2: out[b][r] = b2[r] + sum_d W2[r][d] * hid[d][b].  1 block x 256.
// ---------------------------------------------------------------------------
__global__ __launch_bounds__(256) void head2_kernel(
    const float* __restrict__ W2, const float* __restrict__ b2,
    const float* __restrict__ hid, float* __restrict__ out)
{
  const int tid  = threadIdx.x;
  const int lane = tid & 63;
  const int w    = tid >> 6;                  // 0..3
  const int kbeg = __builtin_amdgcn_readfirstlane(w * 64);
  float xr[64];
  const float* hp = hid + (size_t)kbeg * BB + lane;
  #pragma unroll
  for (int i = 0; i < 64; ++i) xr[i] = hp[i * BB];
  __shared__ float red[4][NCLS][64];
  #pragma unroll
  for (int r = 0; r < NCLS; ++r) {
    const float* Wr = W2 + (size_t)r * DFF + kbeg;
    float a = 0.f;
    #pragma unroll
    for (int k = 0; k < 64; ++k) a = fmaf(Wr[k], xr[k], a);
    red[w][r][lane] = a;
  }
  __syncthreads();
  for (int it = 0; it < 5; ++it) {
    const int item = tid + it * 256;          // 18*64 = 1152 items
    if (item < NCLS * 64) {
      const int r = item >> 6, b = item & 63;
      float s = red[0][r][b] + red[1][r][b] + red[2][r][b] + red[3][r][b];
      out[(size_t)b * NCLS + r] = s + b2[r];
    }
  }
}

// ---------------------------------------------------------------------------
extern "C" void kernel_launch(void* const* d_in, const int* in_sizes, int n_in,
                              void* d_out, int out_size, void* d_ws, size_t ws_size,
                              hipStream_t stream)
{
  const int*   tokens = (const int*)  d_in[0];
  const int*   tags   = (const int*)  d_in[1];
  const float* emb    = (const float*)d_in[2];
  const float* W_ih   = (const float*)d_in[3];
  const float* W_hh   = (const float*)d_in[4];
  const float* b_ih   = (const float*)d_in[5];
  const float* b_hh   = (const float*)d_in[6];
  const float* W1     = (const float*)d_in[7];
  const float* b1     = (const float*)d_in[8];
  const float* W2     = (const float*)d_in[9];
  const float* b2     = (const float*)d_in[10];
  float* out = (float*)d_out;

  // ws layout: [xW chunk][hA][hB][cst][hF][hid][flags]
  const size_t per_t = (size_t)G4H * BB * sizeof(float);   // 512 KB per timestep
  int TCH = 8;
  for (int c = 256; c >= 8; c >>= 1) {
    if ((size_t)c * per_t + (4u << 20) <= ws_size) { TCH = c; break; }
  }
  char* p = (char*)d_ws;
  float* xW  = (float*)p;  p += (size_t)TCH * per_t;
  float* hA  = (float*)p;  p += (size_t)HH * BB * sizeof(float);
  float* hB  = (float*)p;  p += (size_t)HH * BB * sizeof(float);
  float* cst = (float*)p;  p += (size_t)HH * BB * sizeof(float);
  float* hF  = (float*)p;  p += (size_t)HH * BB * sizeof(float);
  float* hid = (float*)p;  p += (size_t)DFF * BB * sizeof(float);
  unsigned int* flags = (unsigned int*)p;      // 256 * 16 dwords = 16 KB

  (void)hipMemsetAsync(hA,  0, (size_t)HH * BB * sizeof(float), stream); // h0 = 0
  (void)hipMemsetAsync(cst, 0, (size_t)HH * BB * sizeof(float), stream); // c0 = 0

  for (int c0 = 0; c0 < TT; c0 += TCH) {
    xproj_kernel<<<dim3((unsigned)TCH * 128), dim3(256), 0, stream>>>(
        tokens, tags, emb, W_ih, b_ih, b_hh, xW, c0);
    (void)hipMemsetAsync(flags, 0, NBLK * 16 * sizeof(unsigned int), stream);
    {
      int t0 = c0, nsteps = TCH;
      void* args[] = { (void*)&tags, (void*)&W_hh, (void*)&xW,
                       (void*)&hA, (void*)&hB, (void*)&cst, (void*)&hF,
                       (void*)&flags, (void*)&t0, (void*)&nsteps };
      hipLaunchCooperativeKernel((const void*)lstm_seq_kernel,
                                 dim3(NBLK), dim3(1024), args, 0, stream);
    }
  }
  head1_kernel<<<dim3(32), dim3(1024), 0, stream>>>(W1, b1, hF, hid);
  head2_kernel<<<dim3(1), dim3(256), 0, stream>>>(W2, b2, hid, out);
}